// Round 7
// baseline (252.306 us; speedup 1.0000x reference)
//
#include <hip/hip_runtime.h>
#include <hip/hip_bf16.h>

#define BB 8
#define LL 4096
#define NCH 8192
#define IDIM 256
#define KDIM 512
#define ODIM 512
#define NDIR 6
#define TOT (BB * LL)  // 32768
#define MT 64          // m-tile rows

typedef short short8 __attribute__((ext_vector_type(8)));
typedef float floatx4 __attribute__((ext_vector_type(4)));

// ws layout (ints):
//   [0..7]               cnt per dir (atomic cursors)
//   [64 .. 64+6T)        idx_by_slot  (slot -> token), slot = d*TOT + pos
//   [64+6T .. 64+12T)    rows_by_slot (r0 | r1<<16)
//   [WBF_OFF ...)        bf16 W copy (3.1 MB)
#define IDX_OFF 64
#define ROWS_OFF (64 + NDIR * TOT)
#define WBF_OFF (64 + 2 * NDIR * TOT)
#define W_ELEMS (NDIR * ODIM * KDIM)  // 1,572,864
#define N_W8 (W_ELEMS / 8)            // 196,608

// ---- Kernel 1: bucket tokens (blocks 0..127) + cvt W fp32->bf16 (rest) ----
__global__ __launch_bounds__(256) void prep_kernel(
    const int* __restrict__ vec, const int* __restrict__ child_l,
    const int* __restrict__ child_r, const int* __restrict__ drev,
    const int* __restrict__ dmap, const float* __restrict__ W,
    int* __restrict__ ws) {
  int bid = blockIdx.x;
  int tid = threadIdx.x;
  if (bid < TOT / 256) {
    __shared__ int lcnt[8];
    __shared__ int gbase[8];
    if (tid < 8) lcnt[tid] = 0;
    __syncthreads();
    int t = bid * 256 + tid;
    int l = t & (LL - 1);
    int v = vec[t];
    int dir = dmap[v] & 7;
    int sw = drev[v];
    int cl = child_l[l];
    int cr = child_r[l];
    int r0 = sw ? cr : cl;  // first half of x
    int r1 = sw ? cl : cr;  // second half
    int pos = atomicAdd(&lcnt[dir], 1);
    __syncthreads();
    if (tid < 8) gbase[tid] = lcnt[tid] ? atomicAdd(&ws[tid], lcnt[tid]) : 0;
    __syncthreads();
    int slot = dir * TOT + gbase[dir] + pos;
    ws[IDX_OFF + slot] = t;
    ws[ROWS_OFF + slot] = r0 | (r1 << 16);
  } else {
    int gid = (bid - TOT / 256) * 256 + tid;  // < N_W8
    __hip_bfloat16* W_bf = (__hip_bfloat16*)(ws + WBF_OFF);
    const floatx4* s = (const floatx4*)W;
    floatx4 a = s[2 * gid];
    floatx4 b = s[2 * gid + 1];
    union { short8 v; __hip_bfloat16 h[8]; } u;
    u.h[0] = __float2bfloat16(a[0]); u.h[1] = __float2bfloat16(a[1]);
    u.h[2] = __float2bfloat16(a[2]); u.h[3] = __float2bfloat16(a[3]);
    u.h[4] = __float2bfloat16(b[0]); u.h[5] = __float2bfloat16(b[1]);
    u.h[6] = __float2bfloat16(b[2]); u.h[7] = __float2bfloat16(b[3]);
    ((short8*)W_bf)[gid] = u.v;
  }
}

// ---- Kernel 2: grouped GEMM, barrier-free register pipeline ----
// Block = 4 independent waves (2m x 2n), wave-tile 32x64, acc[2][4] of
// mfma_f32_16x16x32_bf16. No LDS, no __syncthreads: each wave loads its own
// fragments (A: fp32 gathered rows of `last`, cvt in-register; B: bf16 W_bf)
// with explicit depth-1 double-buffered prefetch -> loads stay in flight
// during MFMA, compiler emits fine-grained vmcnt (no barrier drain).
__global__ __launch_bounds__(256) void gemm_kernel(
    const float* __restrict__ last, const float* __restrict__ bias,
    const float* __restrict__ alpha_m, const int* __restrict__ ws,
    float* __restrict__ out) {
  // tile -> (dir, m_base) from per-dir counts (64-aligned tile ranges)
  const int mt = blockIdx.y;
  const int nt = blockIdx.x;
  int d = -1, count = 0, m_base = 0;
  {
    int tb = 0;
    for (int dd = 0; dd < NDIR; ++dd) {
      int c = ws[dd];
      int ntile = (c + MT - 1) / MT;
      if (mt < tb + ntile) { d = dd; count = c; m_base = (mt - tb) * MT; break; }
      tb += ntile;
    }
  }
  if (d < 0) return;

  const __hip_bfloat16* W_bf = (const __hip_bfloat16*)(ws + WBF_OFF);
  const int* idx = ws + IDX_OFF + d * TOT;
  const int* rows = ws + ROWS_OFF + d * TOT;

  const int tid = threadIdx.x;
  const int wave = __builtin_amdgcn_readfirstlane(tid >> 6);
  const int lane = tid & 63;
  const int lane15 = lane & 15;
  const int quad = lane >> 4;
  const int wm = wave >> 1;
  const int wn = wave & 1;
  const int n_blk = nt * 128;

  // A fragment base pointers (fp32, gathered rows; +quad*8 k offset)
  const float* paf0[2];
  const float* paf1[2];
#pragma unroll
  for (int i = 0; i < 2; ++i) {
    int lr = m_base + wm * 32 + i * 16 + lane15;
    if (lr >= count) lr = count - 1;
    int t = idx[lr] & (TOT - 1);
    int rr = rows[lr];
    int b = t >> 12;  // L=4096
    int r0 = rr & (NCH - 1);
    int r1 = (rr >> 16) & (NCH - 1);
    paf0[i] = last + (long long)(b * NCH + r0) * IDIM + quad * 8;
    paf1[i] = last + (long long)(b * NCH + r1) * IDIM + quad * 8;
  }
  // B fragment base pointers (bf16; +quad*8 k offset)
  const __hip_bfloat16* pb[4];
#pragma unroll
  for (int j = 0; j < 4; ++j)
    pb[j] = W_bf + (long long)(d * ODIM + n_blk + wn * 64 + j * 16 + lane15) * KDIM + quad * 8;

  floatx4 acc[2][4] = {};

  // register pipeline buffers
  floatx4 ar[2][2][2];  // [buf][frag][half of 8 floats]
  short8 br[2][4];      // [buf][frag]

#pragma unroll
  for (int i = 0; i < 2; ++i) {
    ar[0][i][0] = *(const floatx4*)(paf0[i]);
    ar[0][i][1] = *(const floatx4*)(paf0[i] + 4);
  }
#pragma unroll
  for (int j = 0; j < 4; ++j) br[0][j] = *(const short8*)(pb[j]);

#pragma unroll
  for (int kt = 0; kt < 16; ++kt) {
    const int cur = kt & 1;
    const int nxt = cur ^ 1;
    if (kt < 15) {
      const int kn = kt + 1;
#pragma unroll
      for (int i = 0; i < 2; ++i) {
        const float* p = (kn < 8) ? paf0[i] + kn * 32 : paf1[i] + (kn - 8) * 32;
        ar[nxt][i][0] = *(const floatx4*)(p);
        ar[nxt][i][1] = *(const floatx4*)(p + 4);
      }
#pragma unroll
      for (int j = 0; j < 4; ++j) br[nxt][j] = *(const short8*)(pb[j] + kn * 32);
    }
    short8 a[2];
#pragma unroll
    for (int i = 0; i < 2; ++i) {
      union { short8 v; __hip_bfloat16 h[8]; } u;
      floatx4 x0 = ar[cur][i][0];
      floatx4 x1 = ar[cur][i][1];
      u.h[0] = __float2bfloat16(x0[0]); u.h[1] = __float2bfloat16(x0[1]);
      u.h[2] = __float2bfloat16(x0[2]); u.h[3] = __float2bfloat16(x0[3]);
      u.h[4] = __float2bfloat16(x1[0]); u.h[5] = __float2bfloat16(x1[1]);
      u.h[6] = __float2bfloat16(x1[2]); u.h[7] = __float2bfloat16(x1[3]);
      a[i] = u.v;
    }
#pragma unroll
    for (int i = 0; i < 2; ++i)
#pragma unroll
      for (int j = 0; j < 4; ++j)
        acc[i][j] = __builtin_amdgcn_mfma_f32_16x16x32_bf16(a[i], br[cur][j], acc[i][j], 0, 0, 0);
  }

  // ---- epilogue: bias + leaky relu, scatter rows by token ----
  const float alpha = alpha_m[d];
  float bj[4];
#pragma unroll
  for (int j = 0; j < 4; ++j)
    bj[j] = bias[d * ODIM + n_blk + wn * 64 + j * 16 + lane15];

#pragma unroll
  for (int i = 0; i < 2; ++i) {
#pragma unroll
    for (int reg = 0; reg < 4; ++reg) {
      int row_id = m_base + wm * 32 + i * 16 + quad * 4 + reg;
      if (row_id >= count) continue;
      int t = idx[row_id] & (TOT - 1);
      float* orow = out + (long long)t * ODIM + n_blk + wn * 64;
#pragma unroll
      for (int j = 0; j < 4; ++j) {
        float y = acc[i][j][reg] + bj[j];
        y = y > 0.f ? y : alpha * y;
        orow[j * 16 + lane15] = y;
      }
    }
  }
}

extern "C" void kernel_launch(void* const* d_in, const int* in_sizes, int n_in,
                              void* d_out, int out_size, void* d_ws, size_t ws_size,
                              hipStream_t stream) {
  const float* last = (const float*)d_in[0];
  const float* W = (const float*)d_in[1];
  const float* bias = (const float*)d_in[2];
  const float* alpha = (const float*)d_in[3];
  const int* child_l = (const int*)d_in[4];
  const int* child_r = (const int*)d_in[5];
  const int* vec = (const int*)d_in[6];
  const int* drev = (const int*)d_in[7];
  const int* dmap = (const int*)d_in[8];

  int* ws = (int*)d_ws;

  hipMemsetAsync(ws, 0, 32, stream);
  prep_kernel<<<TOT / 256 + N_W8 / 256, 256, 0, stream>>>(
      vec, child_l, child_r, drev, dmap, W, ws);
  dim3 grid(ODIM / 128, TOT / MT + NDIR, 1);
  gemm_kernel<<<grid, 256, 0, stream>>>(last, bias, alpha, ws, (float*)d_out);
}

// Round 8
// 173.883 us; speedup vs baseline: 1.4510x; 1.4510x over previous
//
#include <hip/hip_runtime.h>
#include <hip/hip_bf16.h>

#define BB 8
#define LL 4096
#define NCH 8192
#define IDIM 256
#define KDIM 512
#define ODIM 512
#define NDIR 6
#define TOT (BB * LL)  // 32768
#define MT 128         // m-tile rows

typedef short short8 __attribute__((ext_vector_type(8)));
typedef float floatx4 __attribute__((ext_vector_type(4)));

// ws layout (ints):
//   [0..7]               cnt per dir (atomic cursors)
//   [64 .. 64+6T)        idx_by_slot  (slot -> token), slot = d*TOT + pos
//   [64+6T .. 64+12T)    rows_by_slot (r0 | r1<<16)
//   [LASTBF_OFF ...)     bf16 last copy (33.5 MB), then bf16 W copy (3.1 MB)
#define IDX_OFF 64
#define ROWS_OFF (64 + NDIR * TOT)
#define LASTBF_OFF (64 + 2 * NDIR * TOT)
#define LAST_ELEMS (BB * NCH * IDIM)  // 16,777,216
#define W_ELEMS (NDIR * ODIM * KDIM)  // 1,572,864
#define N_LAST8 (LAST_ELEMS / 8)      // 2,097,152
#define N_W8 (W_ELEMS / 8)            // 196,608
#define SCAT_BLK (TOT / 256)          // 128
#define CVTL_BLK (N_LAST8 / 256)      // 8192
#define CVTW_BLK (N_W8 / 256)         // 768

__device__ inline void async_copy16(const void* g, void* l) {
  __builtin_amdgcn_global_load_lds(
      (const __attribute__((address_space(1))) void*)g,
      (__attribute__((address_space(3))) void*)l, 16, 0, 0);
}

__device__ inline void cvt8(const float* __restrict__ src,
                            __hip_bfloat16* __restrict__ dst, int i) {
  const floatx4* s = (const floatx4*)src;
  floatx4 a = s[2 * i];
  floatx4 b = s[2 * i + 1];
  union { short8 v; __hip_bfloat16 h[8]; } u;
  u.h[0] = __float2bfloat16(a[0]); u.h[1] = __float2bfloat16(a[1]);
  u.h[2] = __float2bfloat16(a[2]); u.h[3] = __float2bfloat16(a[3]);
  u.h[4] = __float2bfloat16(b[0]); u.h[5] = __float2bfloat16(b[1]);
  u.h[6] = __float2bfloat16(b[2]); u.h[7] = __float2bfloat16(b[3]);
  ((short8*)dst)[i] = u.v;
}

// ---- Kernel 1 (fused prep): scatter buckets | cvt last | cvt W ----
__global__ __launch_bounds__(256) void prep_kernel(
    const int* __restrict__ vec, const int* __restrict__ child_l,
    const int* __restrict__ child_r, const int* __restrict__ drev,
    const int* __restrict__ dmap, const float* __restrict__ last,
    const float* __restrict__ W, int* __restrict__ ws) {
  __hip_bfloat16* last_bf = (__hip_bfloat16*)(ws + LASTBF_OFF);
  __hip_bfloat16* W_bf = last_bf + LAST_ELEMS;
  int bid = blockIdx.x;
  int tid = threadIdx.x;
  if (bid < SCAT_BLK) {
    __shared__ int lcnt[8];
    __shared__ int gbase[8];
    if (tid < 8) lcnt[tid] = 0;
    __syncthreads();
    int t = bid * 256 + tid;
    int l = t & (LL - 1);
    int v = vec[t];
    int dir = dmap[v] & 7;
    int sw = drev[v];
    int cl = child_l[l];
    int cr = child_r[l];
    int r0 = sw ? cr : cl;  // first half of x
    int r1 = sw ? cl : cr;  // second half
    int pos = atomicAdd(&lcnt[dir], 1);
    __syncthreads();
    if (tid < 8) gbase[tid] = lcnt[tid] ? atomicAdd(&ws[tid], lcnt[tid]) : 0;
    __syncthreads();
    int slot = dir * TOT + gbase[dir] + pos;
    ws[IDX_OFF + slot] = t;
    ws[ROWS_OFF + slot] = r0 | (r1 << 16);
  } else if (bid < SCAT_BLK + CVTL_BLK) {
    cvt8(last, last_bf, (bid - SCAT_BLK) * 256 + tid);
  } else {
    cvt8(W, W_bf, (bid - SCAT_BLK - CVTL_BLK) * 256 + tid);
  }
}

// ---- Kernel 2: grouped GEMM, 128x128 tile, BK=64, DOUBLE-buffered LDS ----
// 4 waves (2x2), wave 64x64 via 4x4 mfma_f32_16x16x32_bf16.
// One __syncthreads per chunk: issue chunk k+1 into the other buffer, then
// MFMA chunk k -> the barrier's vmcnt(0) drain lands after a full compute
// phase instead of immediately after issue (r4 paid 2 barriers/chunk).
// LDS rows 64 elems (8 x 16B units); stored unit = g_unit ^ (row&7) (on the
// global source side so staging stays lane-contiguous); proven in r4.
__global__ __launch_bounds__(256, 2) void gemm_kernel(
    const float* __restrict__ bias, const float* __restrict__ alpha_m,
    const int* __restrict__ ws, float* __restrict__ out) {
  __shared__ __hip_bfloat16 Als[2][128 * 64];  // 16 KB x2
  __shared__ __hip_bfloat16 Bls[2][128 * 64];  // 16 KB x2 (64 KB total)

  // tile -> (dir, m_base) from per-dir counts (128-aligned tile ranges)
  const int mt = blockIdx.y;
  const int nt = blockIdx.x;
  int d = -1, count = 0, m_base = 0;
  {
    int tb = 0;
    for (int dd = 0; dd < NDIR; ++dd) {
      int c = ws[dd];
      int ntile = (c + MT - 1) / MT;
      if (mt < tb + ntile) { d = dd; count = c; m_base = (mt - tb) * MT; break; }
      tb += ntile;
    }
  }
  if (d < 0) return;

  const __hip_bfloat16* last_bf = (const __hip_bfloat16*)(ws + LASTBF_OFF);
  const __hip_bfloat16* W_bf = last_bf + LAST_ELEMS;
  const int* idx = ws + IDX_OFF + d * TOT;
  const int* rows = ws + ROWS_OFF + d * TOT;

  const int tid = threadIdx.x;
  const int wave = __builtin_amdgcn_readfirstlane(tid >> 6);
  const int lane = tid & 63;
  const int lane15 = lane & 15;
  const int quad = lane >> 4;
  const int wm = wave >> 1;
  const int wn = wave & 1;
  const int n_blk = nt * 128;

  // staging descriptors: per thread 4 A-instrs + 4 B-instrs, 8 rows each
  const __hip_bfloat16* ap0[4];
  const __hip_bfloat16* ap1[4];
  const __hip_bfloat16* bp[4];
  int ldsrow[4];
#pragma unroll
  for (int i = 0; i < 4; ++i) {
    int sr = wave * 32 + i * 8 + (lane >> 3);  // local row 0..127
    ldsrow[i] = (wave * 32 + i * 8) * 64;      // lds elem offset (wave-uniform)
    int lr = m_base + sr;
    if (lr >= count) lr = count - 1;
    int t = idx[lr] & (TOT - 1);
    int rr = rows[lr];
    int b = t >> 12;  // L=4096
    int r0 = rr & (NCH - 1);
    int r1 = (rr >> 16) & (NCH - 1);
    int xu = ((lane & 7) ^ (sr & 7)) * 8;  // swizzled source unit -> elems
    ap0[i] = last_bf + (long long)(b * NCH + r0) * IDIM + xu;
    ap1[i] = last_bf + (long long)(b * NCH + r1) * IDIM + xu;
    bp[i] = W_bf + (long long)(d * ODIM + n_blk + sr) * KDIM + xu;
  }

  floatx4 acc[4][4] = {};
  const int lx = lane15 & 7;  // frag-read swizzle key (row&7)

  // prologue: stage chunk 0 into buf 0
#pragma unroll
  for (int i = 0; i < 4; ++i) {
    async_copy16(ap0[i], &Als[0][ldsrow[i]]);
    async_copy16(bp[i], &Bls[0][ldsrow[i]]);
  }

#pragma unroll
  for (int kt = 0; kt < 8; ++kt) {
    __syncthreads();  // chunk kt visible; prior buffer's reads consumed
    if (kt < 7) {
      const int kn = kt + 1;
      const int nb = kn & 1;
      const int ko = (kn & 3) * 64;
#pragma unroll
      for (int i = 0; i < 4; ++i) {
        const __hip_bfloat16* ga = (kn < 4 ? ap0[i] : ap1[i]) + ko;
        async_copy16(ga, &Als[nb][ldsrow[i]]);
        async_copy16(bp[i] + kn * 64, &Bls[nb][ldsrow[i]]);
      }
    }
    const int c = kt & 1;
#pragma unroll
    for (int s = 0; s < 2; ++s) {
      const int xcol = ((quad + 4 * s) ^ lx) * 8;  // swizzled elem offset
      short8 a[4], b[4];
#pragma unroll
      for (int i = 0; i < 4; ++i)
        a[i] = *(const short8*)&Als[c][(wm * 64 + i * 16 + lane15) * 64 + xcol];
#pragma unroll
      for (int j = 0; j < 4; ++j)
        b[j] = *(const short8*)&Bls[c][(wn * 64 + j * 16 + lane15) * 64 + xcol];
#pragma unroll
      for (int i = 0; i < 4; ++i)
#pragma unroll
        for (int j = 0; j < 4; ++j)
          acc[i][j] = __builtin_amdgcn_mfma_f32_16x16x32_bf16(a[i], b[j], acc[i][j], 0, 0, 0);
    }
  }

  // ---- epilogue: bias + leaky relu, scatter rows by token ----
  const float alpha = alpha_m[d];
  float bj[4];
#pragma unroll
  for (int j = 0; j < 4; ++j)
    bj[j] = bias[d * ODIM + n_blk + wn * 64 + j * 16 + lane15];

#pragma unroll
  for (int i = 0; i < 4; ++i) {
#pragma unroll
    for (int reg = 0; reg < 4; ++reg) {
      int row_id = m_base + wm * 64 + i * 16 + quad * 4 + reg;
      if (row_id >= count) continue;
      int t = idx[row_id] & (TOT - 1);
      float* orow = out + (long long)t * ODIM + n_blk + wn * 64;
#pragma unroll
      for (int j = 0; j < 4; ++j) {
        float y = acc[i][j][reg] + bj[j];
        y = y > 0.f ? y : alpha * y;
        orow[j * 16 + lane15] = y;
      }
    }
  }
}

extern "C" void kernel_launch(void* const* d_in, const int* in_sizes, int n_in,
                              void* d_out, int out_size, void* d_ws, size_t ws_size,
                              hipStream_t stream) {
  const float* last = (const float*)d_in[0];
  const float* W = (const float*)d_in[1];
  const float* bias = (const float*)d_in[2];
  const float* alpha = (const float*)d_in[3];
  const int* child_l = (const int*)d_in[4];
  const int* child_r = (const int*)d_in[5];
  const int* vec = (const int*)d_in[6];
  const int* drev = (const int*)d_in[7];
  const int* dmap = (const int*)d_in[8];

  int* ws = (int*)d_ws;

  hipMemsetAsync(ws, 0, 32, stream);
  prep_kernel<<<SCAT_BLK + CVTL_BLK + CVTW_BLK, 256, 0, stream>>>(
      vec, child_l, child_r, drev, dmap, last, W, ws);
  dim3 grid(ODIM / 128, TOT / MT + NDIR, 1);
  gemm_kernel<<<grid, 256, 0, stream>>>(bias, alpha, ws, (float*)d_out);
}